// Round 7
// baseline (866.338 us; speedup 1.0000x reference)
//
#include <hip/hip_runtime.h>
#include <hip/hip_bf16.h>

#define FRAMES 512
#define BATCH 2048
#define IN_DIM 84
#define HIDDEN 300
#define OUT_DIM 10

#define MT 16            // batch rows per workgroup
#define RSTR 512         // row stride in shorts (g(r,c) = r*512 + 8*(r&7) + c)
#define XCOL 320         // x column base within a row
#define BUFS (MT * RSTR) // shorts per buffer (16 KiB)
#define NT 5             // tiles per wave: t = wv*5 + i (tile 19 zero-weighted)

typedef __attribute__((ext_vector_type(8))) short s8v;
typedef __attribute__((ext_vector_type(4))) short s4v;
typedef __attribute__((ext_vector_type(4))) float f4v;

__device__ __forceinline__ short f2b(float x) {
    __hip_bfloat16 h = __float2bfloat16(x);
    return *reinterpret_cast<short*>(&h);
}
__device__ __forceinline__ float b2f(short s) {
    __hip_bfloat16 h = *reinterpret_cast<__hip_bfloat16*>(&s);
    return __bfloat162float(h);
}
__device__ __forceinline__ float fast_tanh(float z) {
    float ex = __builtin_amdgcn_exp2f(z * 2.88539008177792681f); // exp(2z)
    return fmaf(-2.f, __builtin_amdgcn_rcpf(ex + 1.f), 1.f);
}
__device__ __forceinline__ int g(int r, int c) {   // swizzled LDS index (shorts)
    return r * RSTR + ((r & 7) << 3) + c;          // linear in c -> column adds commute
}

// Swapped-operand step:  D[n][b] = sum_k W[n][k] * h[b][k]
//   A = weight tile (regs/AGPR), B = h fragment (LDS b128), C/D: lane l holds
//   batch=l&15, 4 consecutive hidden cols -> one ds_write_b64 per tile.
// 4 waves (1/SIMD): halves the per-CU LDS read replication vs 8 waves.

__global__ __launch_bounds__(256, 1)
void rnn_kernel(const float* __restrict__ x, const float* __restrict__ h0,
                const float* __restrict__ Wi, const float* __restrict__ Wh,
                const float* __restrict__ Wo, float* __restrict__ out)
{
    __shared__ short lds[2 * BUFS];
    const int tid  = threadIdx.x;
    const int lane = tid & 63;
    const int wv   = tid >> 6;          // wave 0..3
    const int l15  = lane & 15;
    const int lkhi = lane >> 4;         // k-subchunk 0..3 / n_local quad
    const int b0   = blockIdx.x * MT;

    // ---- weight-stationary A-fragments; tile 19 zero via n<HIDDEN guard ----
    s8v w[NT][13];
#pragma unroll
    for (int i = 0; i < NT; ++i) {
        const int n = (wv * NT + i) * 16 + l15;
#pragma unroll
        for (int kf = 0; kf < 10; ++kf) {
            s8v v;
#pragma unroll
            for (int j = 0; j < 8; ++j) {
                int k = kf * 32 + lkhi * 8 + j;
                float f = (n < HIDDEN && k < HIDDEN) ? Wh[n * HIDDEN + k] : 0.f;
                v[j] = f2b(f);
            }
            w[i][kf] = v;
        }
#pragma unroll
        for (int kf = 10; kf < 13; ++kf) {
            s8v v;
#pragma unroll
            for (int j = 0; j < 8; ++j) {
                int k = (kf - 10) * 32 + lkhi * 8 + j;
                float f = (n < HIDDEN && k < IN_DIM) ? Wi[n * IN_DIM + k] : 0.f;
                v[j] = f2b(f);
            }
            w[i][kf] = v;
        }
    }

    // ---- zero both buffers ----
    {
        s4v z = (s4v){0, 0, 0, 0};
        for (int i = tid; i < 2 * BUFS / 4; i += 256)
            ((s4v*)lds)[i] = z;
    }
    __syncthreads();

    // ---- h0 -> buf0, frame-0 x -> buf0 ----
    for (int i = tid; i < MT * HIDDEN; i += 256) {
        int r = i / HIDDEN, c = i % HIDDEN;
        lds[g(r, c)] = f2b(h0[(size_t)(b0 + r) * HIDDEN + c]);
    }
    {
        const float4* xs = reinterpret_cast<const float4*>(x + (size_t)b0 * IN_DIM);
        float4 v0 = xs[tid];
        int r = tid / 21, c4 = (tid % 21) * 4;
        s4v pk = {f2b(v0.x), f2b(v0.y), f2b(v0.z), f2b(v0.w)};
        *reinterpret_cast<s4v*>(&lds[g(r, XCOL + c4)]) = pk;
        if (tid < 80) {
            float4 v1 = xs[256 + tid];
            int vi = 256 + tid; r = vi / 21; c4 = (vi % 21) * 4;
            s4v p1 = {f2b(v1.x), f2b(v1.y), f2b(v1.z), f2b(v1.w)};
            *reinterpret_cast<s4v*>(&lds[g(r, XCOL + c4)]) = p1;
        }
    }

    // ---- per-lane constant bases (shorts) ----
    const int rdh  = g(l15, lkhi * 8);            // B-frag read base
    const int wrb  = g(l15, lkhi * 4);            // h' write base (+t*16, linear in c)
    const int xcb1 = g(tid / 21, XCOL + (tid % 21) * 4);
    const int vi2  = 256 + tid;
    const int xcb2 = g(vi2 / 21, XCOL + (vi2 % 21) * 4);

    // ---- x prefetch pipeline, 2 frames deep ----
    float4 xa0, xa1, xb0, xb1;
    {   // frame 1 preload
        const float4* xs = reinterpret_cast<const float4*>(x + ((size_t)BATCH + b0) * IN_DIM);
        xa0 = xs[tid];
        if (tid < 80) xa1 = xs[256 + tid];
    }
    __syncthreads();

#define STEP(PH, SF, A0, A1, B0, B1)                                            \
    {                                                                           \
        if ((SF) + 2 < FRAMES) {   /* issue load frame SF+2 (consumed next step) */ \
            const float4* xs = reinterpret_cast<const float4*>(                 \
                x + ((size_t)((SF) + 2) * BATCH + b0) * IN_DIM);                \
            B0 = xs[tid];                                                       \
            if (tid < 80) B1 = xs[256 + tid];                                   \
        }                                                                       \
        s8v bf[13];                                                             \
        _Pragma("unroll")                                                       \
        for (int kf = 0; kf < 10; ++kf)                                         \
            bf[kf] = *(const s8v*)&lds[(PH) * BUFS + rdh + kf * 32];            \
        _Pragma("unroll")                                                       \
        for (int j = 0; j < 3; ++j)                                             \
            bf[10 + j] = *(const s8v*)&lds[(PH) * BUFS + rdh + XCOL + j * 32];  \
        f4v acc[NT];                                                            \
        _Pragma("unroll")                                                       \
        for (int i = 0; i < NT; ++i) acc[i] = (f4v){0.f, 0.f, 0.f, 0.f};        \
        _Pragma("unroll")                                                       \
        for (int kf = 0; kf < 13; ++kf) {                                       \
            _Pragma("unroll")                                                   \
            for (int i = 0; i < NT; ++i)                                        \
                acc[i] = __builtin_amdgcn_mfma_f32_16x16x32_bf16(               \
                    w[i][kf], bf[kf], acc[i], 0, 0, 0);                         \
        }                                                                       \
        _Pragma("unroll")                                                       \
        for (int i = 0; i < NT; ++i) {                                          \
            s4v hv;                                                             \
            _Pragma("unroll")                                                   \
            for (int r = 0; r < 4; ++r) hv[r] = f2b(fast_tanh(acc[i][r]));      \
            *(s4v*)&lds[((PH) ^ 1) * BUFS + wrb + (wv * NT + i) * 16] = hv;     \
        }                                                                       \
        if ((SF) + 1 < FRAMES) {   /* commit frame SF+1 (loaded last step) */   \
            s4v pk = {f2b(A0.x), f2b(A0.y), f2b(A0.z), f2b(A0.w)};              \
            *(s4v*)&lds[((PH) ^ 1) * BUFS + xcb1] = pk;                         \
            if (tid < 80) {                                                     \
                s4v p1 = {f2b(A1.x), f2b(A1.y), f2b(A1.z), f2b(A1.w)};          \
                *(s4v*)&lds[((PH) ^ 1) * BUFS + xcb2] = p1;                     \
            }                                                                   \
        }                                                                       \
        __syncthreads();                                                        \
    }

    for (int s = 0; s < FRAMES; s += 2) {
        STEP(0, s,     xa0, xa1, xb0, xb1)
        STEP(1, s + 1, xb0, xb1, xa0, xa1)
    }
#undef STEP

    // ---- epilogue: final h in buf0 (FRAMES even) ----
    float* hout = out + BATCH * OUT_DIM;
    for (int i = tid; i < MT * HIDDEN; i += 256) {
        int r = i / HIDDEN, c = i % HIDDEN;
        hout[(size_t)(b0 + r) * HIDDEN + c] = b2f(lds[g(r, c)]);
    }
    if (tid < MT * OUT_DIM) {
        int r = tid / OUT_DIM, c = tid % OUT_DIM;
        float sum = 0.f;
        for (int k = 0; k < HIDDEN; ++k)
            sum = fmaf(b2f(lds[g(r, k)]), Wo[c * HIDDEN + k], sum);
        out[(b0 + r) * OUT_DIM + c] = sum;
    }
}

extern "C" void kernel_launch(void* const* d_in, const int* in_sizes, int n_in,
                              void* d_out, int out_size, void* d_ws, size_t ws_size,
                              hipStream_t stream) {
    const float* x  = (const float*)d_in[0];
    const float* h0 = (const float*)d_in[1];
    const float* Wi = (const float*)d_in[2];
    const float* Wh = (const float*)d_in[3];
    const float* Wo = (const float*)d_in[4];
    float* out = (float*)d_out;
    rnn_kernel<<<dim3(BATCH / MT), dim3(256), 0, stream>>>(x, h0, Wi, Wh, Wo, out);
}

// Round 8
// 545.736 us; speedup vs baseline: 1.5875x; 1.5875x over previous
//
#include <hip/hip_runtime.h>
#include <hip/hip_bf16.h>

#define FRAMES 512
#define BATCH 2048
#define IN_DIM 84
#define HIDDEN 300
#define OUT_DIM 10

#define MT 16            // batch rows per workgroup
#define RSTR 512         // row stride in shorts (g(r,c) = r*512 + 8*(r&7) + c)
#define XCOL 320         // x column base within a row
#define BUFS (MT * RSTR) // shorts per buffer (16 KiB)
#define NT 3             // tiles per wave: t = wv, wv+8, wv+16 (wv>=3 -> 2 real tiles)

typedef __attribute__((ext_vector_type(8))) short s8v;
typedef __attribute__((ext_vector_type(4))) short s4v;
typedef __attribute__((ext_vector_type(4))) float f4v;

__device__ __forceinline__ short f2b(float x) {
    __hip_bfloat16 h = __float2bfloat16(x);
    return *reinterpret_cast<short*>(&h);
}
__device__ __forceinline__ float b2f(short s) {
    __hip_bfloat16 h = *reinterpret_cast<__hip_bfloat16*>(&s);
    return __bfloat162float(h);
}
__device__ __forceinline__ float fast_tanh(float z) {
    float ex = __builtin_amdgcn_exp2f(z * 2.88539008177792681f); // exp(2z)
    return fmaf(-2.f, __builtin_amdgcn_rcpf(ex + 1.f), 1.f);
}
__device__ __forceinline__ int g(int r, int c) {   // swizzled LDS index (shorts)
    return r * RSTR + ((r & 7) << 3) + c;          // linear in c
}
// write-drain barrier: LDS ordered, global loads stay in flight (no vmcnt drain)
__device__ __forceinline__ void lgkm_barrier() {
    asm volatile("s_waitcnt lgkmcnt(0)" ::: "memory");
    __builtin_amdgcn_s_barrier();
}

// Swapped-operand step:  D[n][b] = sum_k W[n][k] * h[b][k]
//   A = weight tile (AGPR-stationary), B = h fragment (LDS b128), C/D: lane l
//   holds batch=l&15, 4 consecutive hidden cols -> one ds_write_b64 per tile.

__global__ __launch_bounds__(512, 2)
void rnn_kernel(const float* __restrict__ x, const float* __restrict__ h0,
                const float* __restrict__ Wi, const float* __restrict__ Wh,
                const float* __restrict__ Wo, float* __restrict__ out)
{
    __shared__ short lds[2 * BUFS];
    const int tid  = threadIdx.x;
    const int lane = tid & 63;
    const int wv   = tid >> 6;          // wave 0..7
    const int l15  = lane & 15;
    const int lkhi = lane >> 4;         // k-subchunk 0..3 / n_local quad
    const int b0   = blockIdx.x * MT;
    const bool w3  = (wv < 3);          // third tile (t = wv+16) real iff < 19

    // ---- weight-stationary A-fragments (tile >=19 zero via n<HIDDEN) ----
    s8v w[NT][13];
#pragma unroll
    for (int i = 0; i < NT; ++i) {
        const int n = (wv + 8 * i) * 16 + l15;
#pragma unroll
        for (int kf = 0; kf < 10; ++kf) {
            s8v v;
#pragma unroll
            for (int j = 0; j < 8; ++j) {
                int k = kf * 32 + lkhi * 8 + j;
                float f = (n < HIDDEN && k < HIDDEN) ? Wh[n * HIDDEN + k] : 0.f;
                v[j] = f2b(f);
            }
            w[i][kf] = v;
        }
#pragma unroll
        for (int kf = 10; kf < 13; ++kf) {
            s8v v;
#pragma unroll
            for (int j = 0; j < 8; ++j) {
                int k = (kf - 10) * 32 + lkhi * 8 + j;
                float f = (n < HIDDEN && k < IN_DIM) ? Wi[n * IN_DIM + k] : 0.f;
                v[j] = f2b(f);
            }
            w[i][kf] = v;
        }
    }

    // ---- zero both buffers ----
    {
        s4v z = (s4v){0, 0, 0, 0};
        for (int i = tid; i < 2 * BUFS / 4; i += 512)
            ((s4v*)lds)[i] = z;
    }
    __syncthreads();

    // ---- h0 -> buf0, frame-0 x -> buf0 ----
    for (int i = tid; i < MT * HIDDEN; i += 512) {
        int r = i / HIDDEN, c = i % HIDDEN;
        lds[g(r, c)] = f2b(h0[(size_t)(b0 + r) * HIDDEN + c]);
    }
    if (tid < 336) {
        const float4* xs = reinterpret_cast<const float4*>(x + (size_t)b0 * IN_DIM);
        float4 v0 = xs[tid];
        int r = tid / 21, c4 = (tid % 21) * 4;
        s4v pk = {f2b(v0.x), f2b(v0.y), f2b(v0.z), f2b(v0.w)};
        *reinterpret_cast<s4v*>(&lds[g(r, XCOL + c4)]) = pk;
    }

    // ---- per-lane constant bases (shorts) ----
    const int rdh   = g(l15, lkhi * 8);            // B-frag read base
    const int wrb   = g(l15, lkhi * 4);            // h' write base (+t*16)
    const int xti   = (tid < 336) ? tid : 0;       // clamped x-load lane index
    const int xcb1  = g(xti / 21, XCOL + (xti % 21) * 4);
    const bool xact = (tid < 336);

    // frame-1 preload
    float4 xa0, xb0;
    xa0 = reinterpret_cast<const float4*>(x + ((size_t)BATCH + b0) * IN_DIM)[xti];
    __syncthreads();

    // STEP: LOADF -> load frame SF+2 into B; COMMITF -> commit A (frame SF+1)
#define STEP(PH, SF, A0, B0, LOADF, COMMITF)                                    \
    {                                                                           \
        if (LOADF) {                                                            \
            B0 = reinterpret_cast<const float4*>(                               \
                x + ((size_t)((SF) + 2) * BATCH + b0) * IN_DIM)[xti];           \
        }                                                                       \
        s8v bf[13];                                                             \
        _Pragma("unroll")                                                       \
        for (int kf = 0; kf < 10; ++kf)                                         \
            bf[kf] = *(const s8v*)&lds[(PH) * BUFS + rdh + kf * 32];            \
        _Pragma("unroll")                                                       \
        for (int j = 0; j < 3; ++j)                                             \
            bf[10 + j] = *(const s8v*)&lds[(PH) * BUFS + rdh + XCOL + j * 32];  \
        __builtin_amdgcn_s_setprio(1);                                          \
        if (w3) {                                                               \
            f4v a0 = {0,0,0,0}, a1 = {0,0,0,0}, a2 = {0,0,0,0};                 \
            _Pragma("unroll")                                                   \
            for (int kf = 0; kf < 13; ++kf) {                                   \
                a0 = __builtin_amdgcn_mfma_f32_16x16x32_bf16(w[0][kf], bf[kf], a0, 0, 0, 0); \
                a1 = __builtin_amdgcn_mfma_f32_16x16x32_bf16(w[1][kf], bf[kf], a1, 0, 0, 0); \
                a2 = __builtin_amdgcn_mfma_f32_16x16x32_bf16(w[2][kf], bf[kf], a2, 0, 0, 0); \
            }                                                                   \
            __builtin_amdgcn_s_setprio(0);                                      \
            s4v h0v, h1v, h2v;                                                  \
            _Pragma("unroll")                                                   \
            for (int r = 0; r < 4; ++r) {                                       \
                h0v[r] = f2b(fast_tanh(a0[r]));                                 \
                h1v[r] = f2b(fast_tanh(a1[r]));                                 \
                h2v[r] = f2b(fast_tanh(a2[r]));                                 \
            }                                                                   \
            *(s4v*)&lds[((PH) ^ 1) * BUFS + wrb + (wv)      * 16] = h0v;        \
            *(s4v*)&lds[((PH) ^ 1) * BUFS + wrb + (wv + 8)  * 16] = h1v;        \
            *(s4v*)&lds[((PH) ^ 1) * BUFS + wrb + (wv + 16) * 16] = h2v;        \
        } else {                                                                \
            f4v a0 = {0,0,0,0}, a1 = {0,0,0,0};                                 \
            _Pragma("unroll")                                                   \
            for (int kf = 0; kf < 13; ++kf) {                                   \
                a0 = __builtin_amdgcn_mfma_f32_16x16x32_bf16(w[0][kf], bf[kf], a0, 0, 0, 0); \
                a1 = __builtin_amdgcn_mfma_f32_16x16x32_bf16(w[1][kf], bf[kf], a1, 0, 0, 0); \
            }                                                                   \
            __builtin_amdgcn_s_setprio(0);                                      \
            s4v h0v, h1v;                                                       \
            _Pragma("unroll")                                                   \
            for (int r = 0; r < 4; ++r) {                                       \
                h0v[r] = f2b(fast_tanh(a0[r]));                                 \
                h1v[r] = f2b(fast_tanh(a1[r]));                                 \
            }                                                                   \
            *(s4v*)&lds[((PH) ^ 1) * BUFS + wrb + (wv)     * 16] = h0v;         \
            *(s4v*)&lds[((PH) ^ 1) * BUFS + wrb + (wv + 8) * 16] = h1v;         \
        }                                                                       \
        if ((COMMITF) && xact) {                                                \
            s4v pk = {f2b(A0.x), f2b(A0.y), f2b(A0.z), f2b(A0.w)};              \
            *(s4v*)&lds[((PH) ^ 1) * BUFS + xcb1] = pk;                         \
        }                                                                       \
        lgkm_barrier();                                                         \
    }

    // steps 0..509: always load+commit (SF+2 <= 511)
    for (int s = 0; s < FRAMES - 2; s += 2) {
        STEP(0, s,     xa0, xb0, 1, 1)
        STEP(1, s + 1, xb0, xa0, 1, 1)
    }
    // step 510 (PH0): commit frame 511 (in xa0), no load
    STEP(0, 510, xa0, xb0, 0, 1)
    // step 511 (PH1): no commit, no load
    STEP(1, 511, xb0, xa0, 0, 0)
#undef STEP

    // ---- epilogue: final h in buf0 (FRAMES even) ----
    float* hout = out + BATCH * OUT_DIM;
    for (int i = tid; i < MT * HIDDEN; i += 512) {
        int r = i / HIDDEN, c = i % HIDDEN;
        hout[(size_t)(b0 + r) * HIDDEN + c] = b2f(lds[g(r, c)]);
    }
    if (tid < MT * OUT_DIM) {
        int r = tid / OUT_DIM, c = tid % OUT_DIM;
        float sum = 0.f;
        for (int k = 0; k < HIDDEN; ++k)
            sum = fmaf(b2f(lds[g(r, k)]), Wo[c * HIDDEN + k], sum);
        out[(b0 + r) * OUT_DIM + c] = sum;
    }
}

extern "C" void kernel_launch(void* const* d_in, const int* in_sizes, int n_in,
                              void* d_out, int out_size, void* d_ws, size_t ws_size,
                              hipStream_t stream) {
    const float* x  = (const float*)d_in[0];
    const float* h0 = (const float*)d_in[1];
    const float* Wi = (const float*)d_in[2];
    const float* Wh = (const float*)d_in[3];
    const float* Wo = (const float*)d_in[4];
    float* out = (float*)d_out;
    rnn_kernel<<<dim3(BATCH / MT), dim3(512), 0, stream>>>(x, h0, Wi, Wh, Wo, out);
}

// Round 9
// 529.447 us; speedup vs baseline: 1.6363x; 1.0308x over previous
//
#include <hip/hip_runtime.h>
#include <hip/hip_bf16.h>

#define FRAMES 512
#define BATCH 2048
#define IN_DIM 84
#define HIDDEN 300
#define OUT_DIM 10

#define MT 16            // batch rows per workgroup
#define RSTR 512         // row stride in shorts (g(r,c) = r*512 + 8*(r&7) + c)
#define XK 300           // x starts at k=300: K = 300 h + 84 x = 384 = 12*32 exactly
#define KF 12            // K-fragments per step
#define BUFS (MT * RSTR) // shorts per buffer (16 KiB)
#define NT 3             // tiles per wave: t = wv, wv+8, wv+16 (wv>=3 -> 2 real tiles)

typedef __attribute__((ext_vector_type(8))) short s8v;
typedef __attribute__((ext_vector_type(4))) short s4v;
typedef __attribute__((ext_vector_type(4))) float f4v;

__device__ __forceinline__ short f2b(float x) {
    __hip_bfloat16 h = __float2bfloat16(x);
    return *reinterpret_cast<short*>(&h);
}
__device__ __forceinline__ float b2f(short s) {
    __hip_bfloat16 h = *reinterpret_cast<__hip_bfloat16*>(&s);
    return __bfloat162float(h);
}
__device__ __forceinline__ float fast_tanh(float z) {
    float ex = __builtin_amdgcn_exp2f(z * 2.88539008177792681f); // exp(2z)
    return fmaf(-2.f, __builtin_amdgcn_rcpf(ex + 1.f), 1.f);
}
__device__ __forceinline__ int g(int r, int c) {   // swizzled LDS index (shorts)
    return r * RSTR + ((r & 7) << 3) + c;          // linear in c
}
// write-drain barrier: LDS ordered, global loads stay in flight (no vmcnt drain)
__device__ __forceinline__ void lgkm_barrier() {
    asm volatile("s_waitcnt lgkmcnt(0)" ::: "memory");
    __builtin_amdgcn_s_barrier();
}

// Swapped-operand step:  D[n][b] = sum_k W[n][k] * state[b][k],  K = 384
//   state[b][k] = h[b][k] (k<300) | x[b][k-300] (k>=300); weights likewise
//   Wh columns / Wi columns packed into one 12-fragment register file.
//   C/D: lane l holds batch=l&15, 4 consecutive n -> one ds_write_b64 per tile.
//   Tile 18 covers n 288..303: lanes n>=300 (lkhi==3) masked (would clobber x).

__global__ __launch_bounds__(512, 2)
void rnn_kernel(const float* __restrict__ x, const float* __restrict__ h0,
                const float* __restrict__ Wi, const float* __restrict__ Wh,
                const float* __restrict__ Wo, float* __restrict__ out)
{
    __shared__ short lds[2 * BUFS];
    const int tid  = threadIdx.x;
    const int lane = tid & 63;
    const int wv   = tid >> 6;          // wave 0..7
    const int l15  = lane & 15;
    const int lkhi = lane >> 4;         // k-subchunk 0..3 / n_local quad
    const int b0   = blockIdx.x * MT;
    const bool w3  = (wv < 3);          // third tile (t = wv+16 <= 18) real
    const bool t18mask = (wv != 2) || (lkhi != 3);  // tile-18 n>=300 lanes masked

    // ---- weight-stationary A-fragments: packed K (Wh k<300 | Wi k>=300) ----
    s8v w[NT][KF];
#pragma unroll
    for (int i = 0; i < NT; ++i) {
        const int n = (wv + 8 * i) * 16 + l15;
#pragma unroll
        for (int kf = 0; kf < KF; ++kf) {
            s8v v;
#pragma unroll
            for (int j = 0; j < 8; ++j) {
                int k = kf * 32 + lkhi * 8 + j;
                float f = 0.f;
                if (n < HIDDEN) f = (k < XK) ? Wh[n * HIDDEN + k] : Wi[n * IN_DIM + (k - XK)];
                v[j] = f2b(f);
            }
            w[i][kf] = v;
        }
    }

    // ---- zero both buffers ----
    {
        s4v z = (s4v){0, 0, 0, 0};
        for (int i = tid; i < 2 * BUFS / 4; i += 512)
            ((s4v*)lds)[i] = z;
    }
    __syncthreads();

    // ---- h0 -> buf0, frame-0 x -> buf0 ----
    for (int i = tid; i < MT * HIDDEN; i += 512) {
        int r = i / HIDDEN, c = i % HIDDEN;
        lds[g(r, c)] = f2b(h0[(size_t)(b0 + r) * HIDDEN + c]);
    }
    if (tid < 336) {
        const float4* xs = reinterpret_cast<const float4*>(x + (size_t)b0 * IN_DIM);
        float4 v0 = xs[tid];
        int r = tid / 21, c4 = (tid % 21) * 4;
        s4v pk = {f2b(v0.x), f2b(v0.y), f2b(v0.z), f2b(v0.w)};
        *reinterpret_cast<s4v*>(&lds[g(r, XK + c4)]) = pk;
    }

    // ---- per-lane constant bases (shorts) ----
    const int rdh   = g(l15, lkhi * 8);            // B-frag read base (+kf*32)
    const int wrb   = g(l15, lkhi * 4);            // h' write base (+t*16)
    const int xti   = (tid < 336) ? tid : 0;       // clamped x-load lane index
    const int xcb1  = g(xti / 21, XK + (xti % 21) * 4);
    const bool xact = (tid < 336);
    const f4v zero4 = (f4v){0.f, 0.f, 0.f, 0.f};   // persistent C=0 (no per-step init)

    // frame-1 preload
    float4 xa0, xb0;
    xa0 = reinterpret_cast<const float4*>(x + ((size_t)BATCH + b0) * IN_DIM)[xti];
    __syncthreads();

    // STEP: LOADF -> load frame SF+2 into B; COMMITF -> commit A (frame SF+1)
#define STEP(PH, SF, A0, B0, LOADF, COMMITF)                                    \
    {                                                                           \
        if (LOADF) {                                                            \
            B0 = reinterpret_cast<const float4*>(                               \
                x + ((size_t)((SF) + 2) * BATCH + b0) * IN_DIM)[xti];           \
        }                                                                       \
        s8v bf[KF];                                                             \
        _Pragma("unroll")                                                       \
        for (int kf = 0; kf < KF; ++kf)                                         \
            bf[kf] = *(const s8v*)&lds[(PH) * BUFS + rdh + kf * 32];            \
        __builtin_amdgcn_s_setprio(1);                                          \
        if (w3) {                                                               \
            f4v a0 = __builtin_amdgcn_mfma_f32_16x16x32_bf16(w[0][0], bf[0], zero4, 0, 0, 0); \
            f4v a1 = __builtin_amdgcn_mfma_f32_16x16x32_bf16(w[1][0], bf[0], zero4, 0, 0, 0); \
            f4v a2 = __builtin_amdgcn_mfma_f32_16x16x32_bf16(w[2][0], bf[0], zero4, 0, 0, 0); \
            _Pragma("unroll")                                                   \
            for (int kf = 1; kf < KF; ++kf) {                                   \
                a0 = __builtin_amdgcn_mfma_f32_16x16x32_bf16(w[0][kf], bf[kf], a0, 0, 0, 0); \
                a1 = __builtin_amdgcn_mfma_f32_16x16x32_bf16(w[1][kf], bf[kf], a1, 0, 0, 0); \
                a2 = __builtin_amdgcn_mfma_f32_16x16x32_bf16(w[2][kf], bf[kf], a2, 0, 0, 0); \
            }                                                                   \
            __builtin_amdgcn_s_setprio(0);                                      \
            s4v h0v, h1v, h2v;                                                  \
            _Pragma("unroll")                                                   \
            for (int r = 0; r < 4; ++r) {                                       \
                h0v[r] = f2b(fast_tanh(a0[r]));                                 \
                h1v[r] = f2b(fast_tanh(a1[r]));                                 \
                h2v[r] = f2b(fast_tanh(a2[r]));                                 \
            }                                                                   \
            *(s4v*)&lds[((PH) ^ 1) * BUFS + wrb + (wv)      * 16] = h0v;        \
            *(s4v*)&lds[((PH) ^ 1) * BUFS + wrb + (wv + 8)  * 16] = h1v;        \
            if (t18mask)                                                        \
                *(s4v*)&lds[((PH) ^ 1) * BUFS + wrb + (wv + 16) * 16] = h2v;    \
        } else {                                                                \
            f4v a0 = __builtin_amdgcn_mfma_f32_16x16x32_bf16(w[0][0], bf[0], zero4, 0, 0, 0); \
            f4v a1 = __builtin_amdgcn_mfma_f32_16x16x32_bf16(w[1][0], bf[0], zero4, 0, 0, 0); \
            _Pragma("unroll")                                                   \
            for (int kf = 1; kf < KF; ++kf) {                                   \
                a0 = __builtin_amdgcn_mfma_f32_16x16x32_bf16(w[0][kf], bf[kf], a0, 0, 0, 0); \
                a1 = __builtin_amdgcn_mfma_f32_16x16x32_bf16(w[1][kf], bf[kf], a1, 0, 0, 0); \
            }                                                                   \
            __builtin_amdgcn_s_setprio(0);                                      \
            s4v h0v, h1v;                                                       \
            _Pragma("unroll")                                                   \
            for (int r = 0; r < 4; ++r) {                                       \
                h0v[r] = f2b(fast_tanh(a0[r]));                                 \
                h1v[r] = f2b(fast_tanh(a1[r]));                                 \
            }                                                                   \
            *(s4v*)&lds[((PH) ^ 1) * BUFS + wrb + (wv)     * 16] = h0v;         \
            *(s4v*)&lds[((PH) ^ 1) * BUFS + wrb + (wv + 8) * 16] = h1v;         \
        }                                                                       \
        if ((COMMITF) && xact) {                                                \
            s4v pk = {f2b(A0.x), f2b(A0.y), f2b(A0.z), f2b(A0.w)};              \
            *(s4v*)&lds[((PH) ^ 1) * BUFS + xcb1] = pk;                         \
        }                                                                       \
        lgkm_barrier();                                                         \
    }

    // steps 0..509: always load+commit (SF+2 <= 511)
    for (int s = 0; s < FRAMES - 2; s += 2) {
        STEP(0, s,     xa0, xb0, 1, 1)
        STEP(1, s + 1, xb0, xa0, 1, 1)
    }
    // step 510 (PH0): commit frame 511 (in xa0), no load
    STEP(0, 510, xa0, xb0, 0, 1)
    // step 511 (PH1): no commit, no load
    STEP(1, 511, xb0, xa0, 0, 0)
#undef STEP

    // ---- epilogue: final h in buf0 (FRAMES even) ----
    float* hout = out + BATCH * OUT_DIM;
    for (int i = tid; i < MT * HIDDEN; i += 512) {
        int r = i / HIDDEN, c = i % HIDDEN;
        hout[(size_t)(b0 + r) * HIDDEN + c] = b2f(lds[g(r, c)]);
    }
    if (tid < MT * OUT_DIM) {
        int r = tid / OUT_DIM, c = tid % OUT_DIM;
        float sum = 0.f;
        for (int k = 0; k < HIDDEN; ++k)
            sum = fmaf(b2f(lds[g(r, k)]), Wo[c * HIDDEN + k], sum);
        out[(b0 + r) * OUT_DIM + c] = sum;
    }
}

extern "C" void kernel_launch(void* const* d_in, const int* in_sizes, int n_in,
                              void* d_out, int out_size, void* d_ws, size_t ws_size,
                              hipStream_t stream) {
    const float* x  = (const float*)d_in[0];
    const float* h0 = (const float*)d_in[1];
    const float* Wi = (const float*)d_in[2];
    const float* Wh = (const float*)d_in[3];
    const float* Wo = (const float*)d_in[4];
    float* out = (float*)d_out;
    rnn_kernel<<<dim3(BATCH / MT), dim3(512), 0, stream>>>(x, h0, Wi, Wh, Wo, out);
}